// Round 12
// baseline (358.739 us; speedup 1.0000x reference)
//
#include <hip/hip_runtime.h>
#include <hip/hip_bf16.h>

#define NNODES 20000
#define NEDGES 320000
#define NGRAPH 1000

typedef __hip_bfloat16 bf16;
typedef unsigned short u16;
typedef short short8 __attribute__((ext_vector_type(8)));
typedef float f32x4 __attribute__((ext_vector_type(4)));
typedef float f32x2 __attribute__((ext_vector_type(2)));

__device__ __forceinline__ float b2f(bf16 x) { return __bfloat162float(x); }
__device__ __forceinline__ float bu2f(u16 u) { return __uint_as_float(((unsigned)u) << 16); }
__device__ __forceinline__ u16 f2bu(float v) {
    __hip_bfloat16 b = __float2bfloat16(v);  // RNE
    return *reinterpret_cast<u16*>(&b);
}

__device__ __forceinline__ int rfl(int v) { return __builtin_amdgcn_readfirstlane(v); }

// sum over each 16-lane row via DPP row_ror (VALU-only, no LDS pipe)
__device__ __forceinline__ float rowsum16(float v) {
    v += __int_as_float(__builtin_amdgcn_update_dpp(0, __float_as_int(v), 0x128, 0xF, 0xF, true)); // ror:8
    v += __int_as_float(__builtin_amdgcn_update_dpp(0, __float_as_int(v), 0x124, 0xF, 0xF, true)); // ror:4
    v += __int_as_float(__builtin_amdgcn_update_dpp(0, __float_as_int(v), 0x122, 0xF, 0xF, true)); // ror:2
    v += __int_as_float(__builtin_amdgcn_update_dpp(0, __float_as_int(v), 0x121, 0xF, 0xF, true)); // ror:1
    return v;
}

// width-agnostic index fetch (int32 or int64 storage)
__device__ __forceinline__ int idx_at(const void* p, int i, int is64) {
    return is64 ? (int)((const long long*)p)[i] : ((const int*)p)[i];
}

// raw float input fetch (bf16 or fp32 storage)
__device__ __forceinline__ float raw_at(const void* p, size_t i, bool isbf) {
    return isbf ? b2f(((const bf16*)p)[i]) : ((const float*)p)[i];
}

static inline char* align16(char* p) {
    return (char*)(((uintptr_t)p + 15) & ~(uintptr_t)15);
}

// ---------------------------------------------------------------------------
// sniff input encodings (flags[0]: floats bf16?, flags[1]: ei int64?, flags[2]: batch int64?)
// ---------------------------------------------------------------------------
__global__ void sniff_all(const void* __restrict__ x, const void* __restrict__ ei,
                          const void* __restrict__ batch, int* __restrict__ flags) {
    __shared__ int sb[4];
    if (threadIdx.x < 4) sb[threadIdx.x] = 0;
    __syncthreads();
    int gb = 0, gf = 0, ze = 0, zb = 0;
    for (int i = threadIdx.x; i < 8192; i += blockDim.x) {
        float vb = b2f(((const bf16*)x)[i]);
        float vf = ((const float*)x)[i];
        if (fabsf(vb) < 1e4f) gb++;
        if (fabsf(vf) < 1e4f) gf++;
        if (((const int*)ei)[2 * i + 1] == 0) ze++;
        if (((const int*)batch)[2 * i + 1] == 0) zb++;
    }
    atomicAdd(&sb[0], gb); atomicAdd(&sb[1], gf);
    atomicAdd(&sb[2], ze); atomicAdd(&sb[3], zb);
    __syncthreads();
    if (threadIdx.x == 0) {
        flags[0] = (sb[0] >= sb[1]) ? 1 : 0;
        flags[1] = (sb[2] > 6000) ? 1 : 0;
        flags[2] = (sb[3] > 6000) ? 1 : 0;
    }
}

// ---------------------------------------------------------------------------
// fused preprocessing: convert-to-fp32 | ea->bf16 | 4x W fragment-pack |
// DEG zero | POOL/CNT zero. All source reads from RAW inputs.
// ---------------------------------------------------------------------------
struct Segs {
    const void* src[29];
    int off[30];
};

__device__ __forceinline__ void wtp_store(u16* __restrict__ dst, const void* __restrict__ src,
                                          int K, int N, int i, bool isbf) {
    int j = i & 7;
    int lane = (i >> 3) & 63;
    int rest = i >> 9;
    int KB = K >> 5;
    int tile = rest / KB, kbi = rest - tile * KB;
    int l16 = lane & 15, quad = lane >> 4;
    int n = tile * 16 + l16;
    int kk = kbi * 32 + quad * 8 + j;
    dst[i] = f2bu(raw_at(src, (size_t)kk * N + n, isbf));
}

__global__ void preprocess(Segs S, const int* __restrict__ flags,
                           float* __restrict__ conv, int total,
                           u16* __restrict__ eah,
                           u16* __restrict__ wt2l, u16* __restrict__ wt2r,
                           u16* __restrict__ wt3l, u16* __restrict__ wt3r,
                           int* __restrict__ deg, float* __restrict__ poolcnt) {
    int i = blockIdx.x * blockDim.x + threadIdx.x;
    bool isbf = flags[0] != 0;
    if (i < total) {
        int lo = 0, hi = 29;
        while (hi - lo > 1) {
            int mid = (lo + hi) >> 1;
            if (i >= S.off[mid]) lo = mid; else hi = mid;
        }
        conv[i] = raw_at(S.src[lo], i - S.off[lo], isbf);
        return;
    }
    i -= total;
    if (i < NEDGES * 4) {                       // edge_attr -> bf16 (raw read)
        eah[i] = isbf ? ((const u16*)S.src[1])[i] : f2bu(((const float*)S.src[1])[i]);
        return;
    }
    i -= NEDGES * 4;
    if (i < 65536) { wtp_store(wt2l, S.src[9],  256, 256, i, isbf); return; }
    i -= 65536;
    if (i < 65536) { wtp_store(wt2r, S.src[11], 256, 256, i, isbf); return; }
    i -= 65536;
    if (i < 16384) { wtp_store(wt3l, S.src[16], 256, 64, i, isbf); return; }
    i -= 16384;
    if (i < 16384) { wtp_store(wt3r, S.src[18], 256, 64, i, isbf); return; }
    i -= 16384;
    if (i < NNODES) { deg[i] = 0; return; }
    i -= NNODES;
    if (i < NGRAPH * 65) poolcnt[i] = 0.f;
}

// ---------------------------------------------------------------------------
// CSR build: histogram -> shfl-scan -> scatter -> per-dst src-sort.
// CSR entry is int4 (src, ea01, ea23, pad): all edge metadata in one
// sequential 16B load for the agg kernels.
// ---------------------------------------------------------------------------
__global__ void csr_hist(const void* __restrict__ ei, const int* __restrict__ flags,
                         int* __restrict__ deg) {
    int e = blockIdx.x * blockDim.x + threadIdx.x;
    if (e >= NEDGES) return;
    atomicAdd(&deg[idx_at(ei, NEDGES + e, flags[1])], 1);
}

__global__ void csr_scan(const int* __restrict__ deg, int* __restrict__ rowptr,
                         int* __restrict__ cursor) {
    __shared__ int wsum[16];
    __shared__ int wpre[16];
    const int t = threadIdx.x;
    const int wid = t >> 6, lane = t & 63;
    const int base = t * 20;
    int loc[20];
    int s = 0;
#pragma unroll
    for (int j = 0; j < 20; j++) {
        int i = base + j;
        int v = (i < NNODES) ? deg[i] : 0;
        loc[j] = s;
        s += v;
    }
    int incl = s;
#pragma unroll
    for (int o = 1; o < 64; o <<= 1) {
        int n = __shfl_up(incl, o);
        if (lane >= o) incl += n;
    }
    if (lane == 63) wsum[wid] = incl;
    __syncthreads();
    if (wid == 0 && lane < 16) {
        int v = wsum[lane];
        int inc2 = v;
#pragma unroll
        for (int o = 1; o < 16; o <<= 1) {
            int n = __shfl_up(inc2, o);
            if (lane >= o) inc2 += n;
        }
        wpre[lane] = inc2 - v;
    }
    __syncthreads();
    int excl = wpre[wid] + incl - s;
#pragma unroll
    for (int j = 0; j < 20; j++) {
        int i = base + j;
        if (i < NNODES) { rowptr[i] = excl + loc[j]; cursor[i] = excl + loc[j]; }
    }
    if (t == 1023) rowptr[NNODES] = excl + s;
}

__global__ void csr_scatter(const void* __restrict__ ei, const int* __restrict__ flags,
                            const u16* __restrict__ eah,
                            int* __restrict__ cursor, int4* __restrict__ csr) {
    int e = blockIdx.x * blockDim.x + threadIdx.x;
    if (e >= NEDGES) return;
    const int i64 = flags[1];
    int src = idx_at(ei, e, i64), dst = idx_at(ei, NEDGES + e, i64);
    uint2 au = *(const uint2*)&eah[(size_t)e * 4];
    int pos = atomicAdd(&cursor[dst], 1);
    csr[pos] = make_int4(src, (int)au.x, (int)au.y, 0);
}

// ---------------------------------------------------------------------------
// Per-dst src-sort (round 12): 64-lane bitonic shuffle sort of each dst's
// edge list, key = src. All agg waves advance ~1 edge/iter in lockstep, so
// src-ascending order makes the k-th edge of every dst point near
// (k/deg)*N: the GPU-wide instantaneous XL working set shrinks from 10.2MB
// (random, ~40% L2 hit) to ~1-2MB (sweep, L2-resident). Reordering within
// a dst only permutes a commutative fp sum (same nondeterminism as the
// atomic scatter). deg>64 (P ~ 1e-14) left unsorted -- perf-only.
// ---------------------------------------------------------------------------
__global__ __launch_bounds__(256, 4) void csr_sort(const int* __restrict__ rowptr,
                                                   int4* __restrict__ csr) {
    const int lane = threadIdx.x & 63;
    const int dst = rfl(blockIdx.x * 4 + (threadIdx.x >> 6));
    const int i0 = rfl(rowptr[dst]);
    const int i1 = rfl(rowptr[dst + 1]);
    const int n = i1 - i0;
    if (n <= 1 || n > 64) return;
    int key = 0x7fffffff, vy = 0, vz = 0;
    if (lane < n) {
        int4 v = csr[i0 + lane];
        key = v.x; vy = v.y; vz = v.z;
    }
#pragma unroll
    for (int k = 2; k <= 64; k <<= 1) {
#pragma unroll
        for (int j = k >> 1; j >= 1; j >>= 1) {
            int pk = __shfl_xor(key, j);
            int py = __shfl_xor(vy, j);
            int pz = __shfl_xor(vz, j);
            bool lower = (lane & j) == 0;
            bool dir = (lane & k) == 0;          // ascending region (k=64: whole wave)
            bool wantMin = (lower == dir);
            bool take = wantMin ? (pk < key) : (pk > key);
            if (take) { key = pk; vy = py; vz = pz; }
        }
    }
    if (lane < n) csr[i0 + lane] = make_int4(key, vy, vz, 0);
}

// ---------------------------------------------------------------------------
// VALU GEMM (layer 1, CIN=12): XL = X@Wl+bl (bf16), XR = X@Wr+br (fp32)
// ---------------------------------------------------------------------------
template <int TM, int CIN, int DOUT, bool GUARD>
__global__ __launch_bounds__(256, 2) void lin_gemm(
        const float* __restrict__ X,
        const float* __restrict__ Wl, const float* __restrict__ bl,
        const float* __restrict__ Wr, const float* __restrict__ br,
        u16* __restrict__ XL, float* __restrict__ XR) {
    constexpr int CPT = DOUT / 4;
    constexpr int RG = 256 / CPT;
    constexpr int M = RG * TM;
    __shared__ float xs[M * CIN];

    const int t = threadIdx.x;
    const int ct = t % CPT;
    const int rg = t / CPT;
    const int c0 = ct * 4;
    const int r0 = blockIdx.x * M;

    constexpr int C4 = CIN / 4;
    for (int i = t; i < M * C4; i += 256) {
        int r = i / C4, j = i - r * C4;
        float4 v = make_float4(0.f, 0.f, 0.f, 0.f);
        if (!GUARD || (r0 + r) < NNODES)
            v = *(const float4*)&X[(size_t)(r0 + r) * CIN + j * 4];
        *(float4*)&xs[r * CIN + j * 4] = v;
    }
    __syncthreads();

    float4 accL[TM], accR[TM];
#pragma unroll
    for (int m = 0; m < TM; m++) {
        accL[m] = make_float4(0.f, 0.f, 0.f, 0.f);
        accR[m] = make_float4(0.f, 0.f, 0.f, 0.f);
    }
    const float* xbase = &xs[rg * TM * CIN];
#pragma unroll 4
    for (int k = 0; k < CIN; k++) {
        const float4 wl = *(const float4*)&Wl[k * DOUT + c0];
        const float4 wr = *(const float4*)&Wr[k * DOUT + c0];
#pragma unroll
        for (int m = 0; m < TM; m++) {
            float xv = xbase[m * CIN + k];
            accL[m].x = fmaf(xv, wl.x, accL[m].x);
            accL[m].y = fmaf(xv, wl.y, accL[m].y);
            accL[m].z = fmaf(xv, wl.z, accL[m].z);
            accL[m].w = fmaf(xv, wl.w, accL[m].w);
            accR[m].x = fmaf(xv, wr.x, accR[m].x);
            accR[m].y = fmaf(xv, wr.y, accR[m].y);
            accR[m].z = fmaf(xv, wr.z, accR[m].z);
            accR[m].w = fmaf(xv, wr.w, accR[m].w);
        }
    }

    const float4 b4l = *(const float4*)&bl[c0];
    const float4 b4r = *(const float4*)&br[c0];
#pragma unroll
    for (int m = 0; m < TM; m++) {
        int row = r0 + rg * TM + m;
        if (GUARD && row >= NNODES) continue;
        float l0 = accL[m].x + b4l.x, l1 = accL[m].y + b4l.y;
        float l2 = accL[m].z + b4l.z, l3 = accL[m].w + b4l.w;
        uint2 pk;
        pk.x = (unsigned)f2bu(l0) | ((unsigned)f2bu(l1) << 16);
        pk.y = (unsigned)f2bu(l2) | ((unsigned)f2bu(l3) << 16);
        *(uint2*)&XL[(size_t)row * DOUT + c0] = pk;
        float4 r4;
        r4.x = accR[m].x + b4r.x; r4.y = accR[m].y + b4r.y;
        r4.z = accR[m].z + b4r.z; r4.w = accR[m].w + b4r.w;
        *(float4*)&XR[(size_t)row * DOUT + c0] = r4;
    }
}

// ---------------------------------------------------------------------------
// MFMA GEMM (layers 2/3): XL = X@Wl+bl (bf16 out), XR = X@Wr+br (fp32 out).
// ---------------------------------------------------------------------------
template <int N>
__global__ __launch_bounds__(256) void lin_gemm_mfma(
        const float* __restrict__ X,
        const u16* __restrict__ WlP, const float* __restrict__ bl,
        const u16* __restrict__ WrP, const float* __restrict__ br,
        u16* __restrict__ XL, float* __restrict__ XR) {
    constexpr int K = 256;
    constexpr int KB = K / 32;
    constexpr int NTW = N / 64;
    constexpr int XSTR = 264;
    __shared__ u16 xhi[16 * XSTR];
    __shared__ u16 xlo[16 * XSTR];

    const int t = threadIdx.x;
    const int w = t >> 6, lane = t & 63;
    const int quad = lane >> 4, l16 = lane & 15;
    const int m0 = blockIdx.x * 16;
    const int nbase = w * (N / 4);

    for (int idx = t; idx < 16 * 64; idx += 256) {
        int r = idx >> 6, c4 = idx & 63;
        float4 v = *(const float4*)&X[(size_t)(m0 + r) * K + c4 * 4];
        float f[4] = {v.x, v.y, v.z, v.w};
        ushort4 hi, lo;
        u16 h;
        h = f2bu(f[0]); hi.x = h; lo.x = f2bu(f[0] - bu2f(h));
        h = f2bu(f[1]); hi.y = h; lo.y = f2bu(f[1] - bu2f(h));
        h = f2bu(f[2]); hi.z = h; lo.z = f2bu(f[2] - bu2f(h));
        h = f2bu(f[3]); hi.w = h; lo.w = f2bu(f[3] - bu2f(h));
        *(ushort4*)&xhi[r * XSTR + c4 * 4] = hi;
        *(ushort4*)&xlo[r * XSTR + c4 * 4] = lo;
    }
    __syncthreads();

    f32x4 accL[NTW], accR[NTW];
#pragma unroll
    for (int i = 0; i < NTW; i++) {
        accL[i] = (f32x4){0.f, 0.f, 0.f, 0.f};
        accR[i] = (f32x4){0.f, 0.f, 0.f, 0.f};
    }

    const int abase = l16 * XSTR + quad * 8;
#pragma unroll
    for (int kbi = 0; kbi < KB; kbi++) {
        short8 ahi = *(const short8*)&xhi[abase + kbi * 32];
        short8 alo = *(const short8*)&xlo[abase + kbi * 32];
#pragma unroll
        for (int i = 0; i < NTW; i++) {
            int tg = (nbase >> 4) + i;
            size_t off = ((size_t)(tg * KB + kbi) * 64 + lane) * 8;
            short8 bL = *(const short8*)&WlP[off];
            short8 bR = *(const short8*)&WrP[off];
            accL[i] = __builtin_amdgcn_mfma_f32_16x16x32_bf16(ahi, bL, accL[i], 0, 0, 0);
            accL[i] = __builtin_amdgcn_mfma_f32_16x16x32_bf16(alo, bL, accL[i], 0, 0, 0);
            accR[i] = __builtin_amdgcn_mfma_f32_16x16x32_bf16(ahi, bR, accR[i], 0, 0, 0);
            accR[i] = __builtin_amdgcn_mfma_f32_16x16x32_bf16(alo, bR, accR[i], 0, 0, 0);
        }
    }

#pragma unroll
    for (int i = 0; i < NTW; i++) {
        int col = nbase + i * 16 + l16;
        float bLv = bl[col], bRv = br[col];
#pragma unroll
        for (int r = 0; r < 4; r++) {
            int row = m0 + quad * 4 + r;
            XL[(size_t)row * N + col] = f2bu(accL[i][r] + bLv);
            XR[(size_t)row * N + col] = accR[i][r] + bRv;
        }
    }
}

// ---------------------------------------------------------------------------
// Merged-wave GATv2 aggregation, scalarized, packed-f32 math (layers 1/2,
// H=4): one WAVE per dst, all 256 channels (4/lane), 8 edges per iter.
// csr/attrs wave-uniform (scalar loads, SGPR operands); VOP3P dual-FP32
// channel math; DPP rowsum16 reduce. Edges src-sorted per dst (round 12)
// so concurrent waves sweep XL coherently instead of thrashing L2.
// ---------------------------------------------------------------------------
template <bool ELU>
__global__ __launch_bounds__(256, 2) void gat_agg_mw(
        const int* __restrict__ rowptr, const int4* __restrict__ csr,
        const u16* __restrict__ XL, const float* __restrict__ XR,
        const float* __restrict__ We, const float* __restrict__ att,
        const float* __restrict__ bias, float* __restrict__ out) {
    const int lane = threadIdx.x & 63;
    const int dst = rfl(blockIdx.x * 4 + (threadIdx.x >> 6));
    const int c0 = lane * 4;                 // head = lane>>4, 4 channels/lane

    const float4 w0 = *(const float4*)&We[0 * 256 + c0];
    const float4 w1 = *(const float4*)&We[1 * 256 + c0];
    const float4 w2 = *(const float4*)&We[2 * 256 + c0];
    const float4 w3 = *(const float4*)&We[3 * 256 + c0];
    const float4 at = *(const float4*)&att[c0];
    const float4 xr = *(const float4*)&XR[(size_t)dst * 256 + c0];
    const f32x2 w0a = {w0.x, w0.y}, w0b = {w0.z, w0.w};
    const f32x2 w1a = {w1.x, w1.y}, w1b = {w1.z, w1.w};
    const f32x2 w2a = {w2.x, w2.y}, w2b = {w2.z, w2.w};
    const f32x2 w3a = {w3.x, w3.y}, w3b = {w3.z, w3.w};
    const f32x2 ata = {at.x, at.y}, atb = {at.z, at.w};
    const f32x2 xra = {xr.x, xr.y}, xrb = {xr.z, xr.w};

    const int i0 = rfl(rowptr[dst]);
    const int i1 = rfl(rowptr[dst + 1]);

    float l = 0.f;
    f32x2 accA = {0.f, 0.f}, accB = {0.f, 0.f};

    // A0..A3 uniform (SGPR) floats; xu is the per-lane 8B gather.
#define MW_BODY(XU, A0, A1, A2, A3)                                              \
    {                                                                            \
        f32x2 xlA = {__uint_as_float((XU).x << 16),                              \
                     __uint_as_float((XU).x & 0xffff0000u)};                     \
        f32x2 xlB = {__uint_as_float((XU).y << 16),                              \
                     __uint_as_float((XU).y & 0xffff0000u)};                     \
        f32x2 zA = xlA + xra;                                                    \
        zA = A0 * w0a + zA;                                                      \
        zA = A1 * w1a + zA;                                                      \
        zA = A2 * w2a + zA;                                                      \
        zA = A3 * w3a + zA;                                                      \
        f32x2 zB = xlB + xrb;                                                    \
        zB = A0 * w0b + zB;                                                      \
        zB = A1 * w1b + zB;                                                      \
        zB = A2 * w2b + zB;                                                      \
        zB = A3 * w3b + zB;                                                      \
        zA = __builtin_elementwise_max(zA, 0.2f * zA);                           \
        zB = __builtin_elementwise_max(zB, 0.2f * zB);                           \
        f32x2 dv = zA * ata;                                                     \
        dv = zB * atb + dv;                                                      \
        float v = dv.x + dv.y;                                                   \
        v = rowsum16(v);                                                         \
        float p = __expf(v);                                                     \
        l += p;                                                                  \
        accA = p * xlA + accA;                                                   \
        accB = p * xlB + accB;                                                   \
    }

// one sequential 16B CSR entry -> src (gather addr) + 4 uniform attrs
#define MW_LOAD(K)                                                               \
        int4 t##K = csr[e + K];                                                  \
        int sx##K = rfl(t##K.x);                                                 \
        uint2 xu##K = *(const uint2*)&XL[(size_t)sx##K * 256 + c0];              \
        float a##K##0 = __uint_as_float(rfl((int)((unsigned)t##K.y << 16)));     \
        float a##K##1 = __uint_as_float(rfl((int)((unsigned)t##K.y & 0xffff0000u))); \
        float a##K##2 = __uint_as_float(rfl((int)((unsigned)t##K.z << 16)));     \
        float a##K##3 = __uint_as_float(rfl((int)((unsigned)t##K.z & 0xffff0000u)));

    int e = i0;
    for (; e + 8 <= i1; e += 8) {
        MW_LOAD(0) MW_LOAD(1) MW_LOAD(2) MW_LOAD(3)
        MW_LOAD(4) MW_LOAD(5) MW_LOAD(6) MW_LOAD(7)
        MW_BODY(xu0, a00, a01, a02, a03)
        MW_BODY(xu1, a10, a11, a12, a13)
        MW_BODY(xu2, a20, a21, a22, a23)
        MW_BODY(xu3, a30, a31, a32, a33)
        MW_BODY(xu4, a40, a41, a42, a43)
        MW_BODY(xu5, a50, a51, a52, a53)
        MW_BODY(xu6, a60, a61, a62, a63)
        MW_BODY(xu7, a70, a71, a72, a73)
    }
    for (; e + 4 <= i1; e += 4) {
        MW_LOAD(0) MW_LOAD(1) MW_LOAD(2) MW_LOAD(3)
        MW_BODY(xu0, a00, a01, a02, a03)
        MW_BODY(xu1, a10, a11, a12, a13)
        MW_BODY(xu2, a20, a21, a22, a23)
        MW_BODY(xu3, a30, a31, a32, a33)
    }
    for (; e < i1; ++e) {
        MW_LOAD(0)
        MW_BODY(xu0, a00, a01, a02, a03)
    }
#undef MW_LOAD
#undef MW_BODY

    // l is already uniform within each 16-lane head group; acc is per-channel.
    float inv = 1.f / (l + 1e-16f);
    const float4 b4 = *(const float4*)&bias[c0];
    f32x2 oA = accA * inv + (f32x2){b4.x, b4.y};
    f32x2 oB = accB * inv + (f32x2){b4.z, b4.w};
    float o0 = oA.x, o1 = oA.y, o2 = oB.x, o3 = oB.y;
    if (ELU) {
        o0 = o0 > 0.f ? o0 : expf(o0) - 1.f;
        o1 = o1 > 0.f ? o1 : expf(o1) - 1.f;
        o2 = o2 > 0.f ? o2 : expf(o2) - 1.f;
        o3 = o3 > 0.f ? o3 : expf(o3) - 1.f;
    }
    *(float4*)&out[(size_t)dst * 256 + c0] = make_float4(o0, o1, o2, o3);
}

// ---------------------------------------------------------------------------
// Layer-3 aggregation (H=1, Dout=64), 4 dst per block, plain-store epilogue
// (pool atomics removed round 6: they were a 46us coherence wall).
// Edge attrs from the int4 CSR entry; packed-f32 channel math.
// ---------------------------------------------------------------------------
template <bool ELU>
__global__ __launch_bounds__(256, 4) void gat_agg4(
                        const int* __restrict__ rowptr, const int4* __restrict__ csr,
                        const u16* __restrict__ XL, const float* __restrict__ XR,
                        const float* __restrict__ We, const float* __restrict__ att,
                        const float* __restrict__ bias, float* __restrict__ out) {
    const int t = threadIdx.x;
    const int lane = t & 63;
    const int g = lane >> 4;         // edge-group 0..3
    const int k = lane & 15;         // channel-slot
    const int c0 = k * 4;            // this lane's 4 channels of 64
    const int dst = rfl(blockIdx.x * 4 + (t >> 6));   // uniform per wave

    const float4 w0 = *(const float4*)&We[0 * 64 + c0];
    const float4 w1 = *(const float4*)&We[1 * 64 + c0];
    const float4 w2 = *(const float4*)&We[2 * 64 + c0];
    const float4 w3 = *(const float4*)&We[3 * 64 + c0];
    const float4 at = *(const float4*)&att[c0];
    const float4 xr = *(const float4*)&XR[(size_t)dst * 64 + c0];
    const f32x2 w0a = {w0.x, w0.y}, w0b = {w0.z, w0.w};
    const f32x2 w1a = {w1.x, w1.y}, w1b = {w1.z, w1.w};
    const f32x2 w2a = {w2.x, w2.y}, w2b = {w2.z, w2.w};
    const f32x2 w3a = {w3.x, w3.y}, w3b = {w3.z, w3.w};
    const f32x2 ata = {at.x, at.y}, atb = {at.z, at.w};
    const f32x2 xra = {xr.x, xr.y}, xrb = {xr.z, xr.w};

    const int i0 = rfl(rowptr[dst]);
    const int i1 = rfl(rowptr[dst + 1]);
    const int niter = (i1 - i0 + 3) >> 2;

    float l = 0.f;
    f32x2 accA = {0.f, 0.f}, accB = {0.f, 0.f};

#define G4_BODY(E_IDX)                                                           \
    {                                                                            \
        int e_ = (E_IDX);                                                        \
        bool valid_ = e_ < i1;                                                   \
        int4 se_ = csr[valid_ ? e_ : i0];                                        \
        uint2 xu_ = *(const uint2*)&XL[(size_t)se_.x * 64 + c0];                 \
        float A0_ = __uint_as_float((unsigned)se_.y << 16);                      \
        float A1_ = __uint_as_float((unsigned)se_.y & 0xffff0000u);              \
        float A2_ = __uint_as_float((unsigned)se_.z << 16);                      \
        float A3_ = __uint_as_float((unsigned)se_.z & 0xffff0000u);              \
        f32x2 xlA = {__uint_as_float(xu_.x << 16),                               \
                     __uint_as_float(xu_.x & 0xffff0000u)};                      \
        f32x2 xlB = {__uint_as_float(xu_.y << 16),                               \
                     __uint_as_float(xu_.y & 0xffff0000u)};                      \
        f32x2 zA = xlA + xra;                                                    \
        zA = A0_ * w0a + zA;                                                     \
        zA = A1_ * w1a + zA;                                                     \
        zA = A2_ * w2a + zA;                                                     \
        zA = A3_ * w3a + zA;                                                     \
        f32x2 zB = xlB + xrb;                                                    \
        zB = A0_ * w0b + zB;                                                     \
        zB = A1_ * w1b + zB;                                                     \
        zB = A2_ * w2b + zB;                                                     \
        zB = A3_ * w3b + zB;                                                     \
        zA = __builtin_elementwise_max(zA, 0.2f * zA);                           \
        zB = __builtin_elementwise_max(zB, 0.2f * zB);                           \
        f32x2 dv = zA * ata;                                                     \
        dv = zB * atb + dv;                                                      \
        float v_ = dv.x + dv.y;                                                  \
        v_ = rowsum16(v_);                                                       \
        float p_ = valid_ ? __expf(v_) : 0.f;                                    \
        l += p_;                                                                 \
        accA = p_ * xlA + accA;                                                  \
        accB = p_ * xlB + accB;                                                  \
    }

    int it = 0;
    for (; it + 2 <= niter; it += 2) {
        int eb = i0 + g + it * 4;
        G4_BODY(eb)
        G4_BODY(eb + 4)
    }
    if (it < niter) {
        G4_BODY(i0 + g + it * 4)
    }
#undef G4_BODY

    // combine the 4 edge-groups (once per dst)
    l += __shfl_xor(l, 16);      l += __shfl_xor(l, 32);
    accA.x += __shfl_xor(accA.x, 16); accA.x += __shfl_xor(accA.x, 32);
    accA.y += __shfl_xor(accA.y, 16); accA.y += __shfl_xor(accA.y, 32);
    accB.x += __shfl_xor(accB.x, 16); accB.x += __shfl_xor(accB.x, 32);
    accB.y += __shfl_xor(accB.y, 16); accB.y += __shfl_xor(accB.y, 32);

    if (g == 0) {
        float inv = 1.f / (l + 1e-16f);
        const float4 b4 = *(const float4*)&bias[c0];
        float o0 = fmaf(accA.x, inv, b4.x);
        float o1 = fmaf(accA.y, inv, b4.y);
        float o2 = fmaf(accB.x, inv, b4.z);
        float o3 = fmaf(accB.y, inv, b4.w);
        if (ELU) {
            o0 = o0 > 0.f ? o0 : expf(o0) - 1.f;
            o1 = o1 > 0.f ? o1 : expf(o1) - 1.f;
            o2 = o2 > 0.f ? o2 : expf(o2) - 1.f;
            o3 = o3 > 0.f ? o3 : expf(o3) - 1.f;
        }
        *(float4*)&out[(size_t)dst * 64 + c0] = make_float4(o0, o1, o2, o3);
    }
}

// ---------------------------------------------------------------------------
// Fused segmented-mean pool + MLP head: one block (64 threads) per graph.
// batch is SORTED -> contiguous node ranges; zero atomics.
// ---------------------------------------------------------------------------
__global__ void pool_mlp(const float* __restrict__ h,  // [N][64]
                         const void* __restrict__ batch, const int* __restrict__ flags,
                         const float* __restrict__ mW1, const float* __restrict__ mb1,
                         const float* __restrict__ mW2, const float* __restrict__ mb2,
                         const float* __restrict__ mW3, const float* __restrict__ mb3,
                         float* __restrict__ out) {
    __shared__ int se[2];
    __shared__ float g[64], s1[32], s2[16];
    const int b = blockIdx.x, t = threadIdx.x;
    const int is64 = flags[2];
    if (t < 2) {
        // lower_bound(batch, b + t): first i with batch[i] >= target
        int target = b + t;
        int lo = 0, hi = NNODES;
        while (lo < hi) {
            int mid = (lo + hi) >> 1;
            if (idx_at(batch, mid, is64) < target) lo = mid + 1; else hi = mid;
        }
        se[t] = lo;
    }
    __syncthreads();
    const int s = se[0], e = se[1];
    float a = 0.f;
    for (int i = s; i < e; i++) a += h[(size_t)i * 64 + t];
    g[t] = a / fmaxf((float)(e - s), 1.f);
    __syncthreads();
    if (t < 32) {
        float acc = 0.f;
        for (int k = 0; k < 64; k++) acc = fmaf(g[k], mW1[k * 32 + t], acc);
        s1[t] = fmaxf(acc + mb1[t], 0.f);
    }
    __syncthreads();
    if (t < 16) {
        float acc = 0.f;
        for (int k = 0; k < 32; k++) acc = fmaf(s1[k], mW2[k * 16 + t], acc);
        s2[t] = fmaxf(acc + mb2[t], 0.f);
    }
    __syncthreads();
    if (t < 4) {
        float acc = 0.f;
        for (int k = 0; k < 16; k++) acc = fmaf(s2[k], mW3[k * 4 + t], acc);
        out[b * 4 + t] = acc + mb3[t];
    }
}

// ---------------------------------------------------------------------------

extern "C" void kernel_launch(void* const* d_in, const int* in_sizes, int n_in,
                              void* d_out, int out_size, void* d_ws, size_t ws_size,
                              hipStream_t stream) {
    const void* ei    = d_in[1];
    const void* batch = d_in[3];

    // ---- canonicalization table: the 29 float inputs in dict order ----
    int fidx[29];
    fidx[0] = 0;  // x
    fidx[1] = 2;  // edge_attr
    for (int i = 0; i < 21; i++) fidx[2 + i] = 4 + i;
    for (int i = 0; i < 6; i++) fidx[23 + i] = 25 + i;

    Segs S;
    int off = 0;
    for (int i = 0; i < 29; i++) {
        S.src[i] = d_in[fidx[i]];
        S.off[i] = off;
        off += in_sizes[fidx[i]];
    }
    S.off[29] = off;
    const int total = off;

    // ---- workspace layout (16B-aligned sections) ----
    char* p = (char*)d_ws;
    int*   FLAGS  = (int*)p;                 p += 16;
    float* CONV   = (float*)p;               p += sizeof(float) * total;  p = align16(p);
    int*   DEG    = (int*)p;                 p += sizeof(int) * NNODES;
    int*   ROWPTR = (int*)p;                 p += sizeof(int) * (NNODES + 1);
    int*   CURSOR = (int*)p;                 p += sizeof(int) * (NNODES + 1);  p = align16(p);
    int4*  CSR    = (int4*)p;                p += sizeof(int4) * NEDGES;  p = align16(p);
    u16*   EAH    = (u16*)p;                 p += sizeof(u16) * NEDGES * 4;  p = align16(p);
    u16*   WT2L   = (u16*)p;                 p += sizeof(u16) * 256 * 256;
    u16*   WT2R   = (u16*)p;                 p += sizeof(u16) * 256 * 256;
    u16*   WT3L   = (u16*)p;                 p += sizeof(u16) * 64 * 256;
    u16*   WT3R   = (u16*)p;                 p += sizeof(u16) * 64 * 256;  p = align16(p);
    u16*   XLb    = (u16*)p;                 p += sizeof(u16) * NNODES * 256;  p = align16(p);
    float* XRb    = (float*)p;               p += sizeof(float) * NNODES * 256;
    float* ACC    = (float*)p;               p += sizeof(float) * NNODES * 256;
    float* POOL   = (float*)p;               p += sizeof(float) * NGRAPH * 64;
    float* CNT    = (float*)p;               p += sizeof(float) * NGRAPH;

    const float* CX  = CONV + S.off[0];
    const float* CP[21];
    for (int i = 0; i < 21; i++) CP[i] = CONV + S.off[2 + i];
    const float* CmW1 = CONV + S.off[23];
    const float* Cmb1 = CONV + S.off[24];
    const float* CmW2 = CONV + S.off[25];
    const float* Cmb2 = CONV + S.off[26];
    const float* CmW3 = CONV + S.off[27];
    const float* Cmb3 = CONV + S.off[28];

    // ---- sniff + fused preprocessing (convert/ea/W-pack/zero-init) ----
    sniff_all<<<1, 256, 0, stream>>>(d_in[0], ei, batch, FLAGS);
    int pre_total = total + NEDGES * 4 + 65536 * 2 + 16384 * 2 + NNODES + NGRAPH * 65;
    preprocess<<<(pre_total + 255) / 256, 256, 0, stream>>>(
        S, FLAGS, CONV, total, EAH, WT2L, WT2R, WT3L, WT3R, DEG, POOL);

    // ---- CSR build (graph identical across layers: build once; attrs folded in) ----
    csr_hist<<<(NEDGES + 255) / 256, 256, 0, stream>>>(ei, FLAGS, DEG);
    csr_scan<<<1, 1024, 0, stream>>>(DEG, ROWPTR, CURSOR);
    csr_scatter<<<(NEDGES + 255) / 256, 256, 0, stream>>>(ei, FLAGS, EAH, CURSOR, CSR);
    csr_sort<<<NNODES / 4, 256, 0, stream>>>(ROWPTR, CSR);

    // ---- layer 1: x (N x 12) -> ACC (N x 256), ELU ----
    lin_gemm<4, 12, 256, false><<<NNODES / 16, 256, 0, stream>>>(CX, CP[0], CP[1], CP[2], CP[3], XLb, XRb);
    gat_agg_mw<true><<<NNODES / 4, 256, 0, stream>>>(ROWPTR, CSR, XLb, XRb,
        CP[4], CP[5], CP[6], ACC);

    // ---- layer 2: ACC (N x 256) -> ACC, ELU (MFMA GEMM) ----
    lin_gemm_mfma<256><<<NNODES / 16, 256, 0, stream>>>(ACC, WT2L, CP[8], WT2R, CP[10], XLb, XRb);
    gat_agg_mw<true><<<NNODES / 4, 256, 0, stream>>>(ROWPTR, CSR, XLb, XRb,
        CP[11], CP[12], CP[13], ACC);

    // ---- layer 3: ACC (N x 256) -> h (N x 64), plain stores (no atomics) ----
    lin_gemm_mfma<64><<<NNODES / 16, 256, 0, stream>>>(ACC, WT3L, CP[15], WT3R, CP[17], XLb, XRb);
    gat_agg4<false><<<NNODES / 4, 256, 0, stream>>>(ROWPTR, CSR, XLb, XRb,
        CP[18], CP[19], CP[20], ACC);

    // ---- segmented mean-pool (sorted batch) + MLP head, fused ----
    pool_mlp<<<NGRAPH, 64, 0, stream>>>(ACC, batch, FLAGS,
        CmW1, Cmb1, CmW2, Cmb2, CmW3, Cmb3, (float*)d_out);
}

// Round 13
// 341.883 us; speedup vs baseline: 1.0493x; 1.0493x over previous
//
#include <hip/hip_runtime.h>
#include <hip/hip_bf16.h>

#define NNODES 20000
#define NEDGES 320000
#define NGRAPH 1000

typedef __hip_bfloat16 bf16;
typedef unsigned short u16;
typedef short short8 __attribute__((ext_vector_type(8)));
typedef float f32x4 __attribute__((ext_vector_type(4)));
typedef float f32x2 __attribute__((ext_vector_type(2)));

__device__ __forceinline__ float b2f(bf16 x) { return __bfloat162float(x); }
__device__ __forceinline__ float bu2f(u16 u) { return __uint_as_float(((unsigned)u) << 16); }
__device__ __forceinline__ u16 f2bu(float v) {
    __hip_bfloat16 b = __float2bfloat16(v);  // RNE
    return *reinterpret_cast<u16*>(&b);
}

__device__ __forceinline__ int rfl(int v) { return __builtin_amdgcn_readfirstlane(v); }

// sum over each 16-lane row via DPP row_ror (VALU-only, no LDS pipe)
__device__ __forceinline__ float rowsum16(float v) {
    v += __int_as_float(__builtin_amdgcn_update_dpp(0, __float_as_int(v), 0x128, 0xF, 0xF, true)); // ror:8
    v += __int_as_float(__builtin_amdgcn_update_dpp(0, __float_as_int(v), 0x124, 0xF, 0xF, true)); // ror:4
    v += __int_as_float(__builtin_amdgcn_update_dpp(0, __float_as_int(v), 0x122, 0xF, 0xF, true)); // ror:2
    v += __int_as_float(__builtin_amdgcn_update_dpp(0, __float_as_int(v), 0x121, 0xF, 0xF, true)); // ror:1
    return v;
}

// width-agnostic index fetch (int32 or int64 storage)
__device__ __forceinline__ int idx_at(const void* p, int i, int is64) {
    return is64 ? (int)((const long long*)p)[i] : ((const int*)p)[i];
}

// raw float input fetch (bf16 or fp32 storage)
__device__ __forceinline__ float raw_at(const void* p, size_t i, bool isbf) {
    return isbf ? b2f(((const bf16*)p)[i]) : ((const float*)p)[i];
}

static inline char* align16(char* p) {
    return (char*)(((uintptr_t)p + 15) & ~(uintptr_t)15);
}

// ---------------------------------------------------------------------------
// sniff input encodings (flags[0]: floats bf16?, flags[1]: ei int64?, flags[2]: batch int64?)
// ---------------------------------------------------------------------------
__global__ void sniff_all(const void* __restrict__ x, const void* __restrict__ ei,
                          const void* __restrict__ batch, int* __restrict__ flags) {
    __shared__ int sb[4];
    if (threadIdx.x < 4) sb[threadIdx.x] = 0;
    __syncthreads();
    int gb = 0, gf = 0, ze = 0, zb = 0;
    for (int i = threadIdx.x; i < 8192; i += blockDim.x) {
        float vb = b2f(((const bf16*)x)[i]);
        float vf = ((const float*)x)[i];
        if (fabsf(vb) < 1e4f) gb++;
        if (fabsf(vf) < 1e4f) gf++;
        if (((const int*)ei)[2 * i + 1] == 0) ze++;
        if (((const int*)batch)[2 * i + 1] == 0) zb++;
    }
    atomicAdd(&sb[0], gb); atomicAdd(&sb[1], gf);
    atomicAdd(&sb[2], ze); atomicAdd(&sb[3], zb);
    __syncthreads();
    if (threadIdx.x == 0) {
        flags[0] = (sb[0] >= sb[1]) ? 1 : 0;
        flags[1] = (sb[2] > 6000) ? 1 : 0;
        flags[2] = (sb[3] > 6000) ? 1 : 0;
    }
}

// ---------------------------------------------------------------------------
// fused preprocessing: convert-to-fp32 | ea->bf16 | 4x W fragment-pack |
// DEG zero | POOL/CNT zero. All source reads from RAW inputs.
// ---------------------------------------------------------------------------
struct Segs {
    const void* src[29];
    int off[30];
};

__device__ __forceinline__ void wtp_store(u16* __restrict__ dst, const void* __restrict__ src,
                                          int K, int N, int i, bool isbf) {
    int j = i & 7;
    int lane = (i >> 3) & 63;
    int rest = i >> 9;
    int KB = K >> 5;
    int tile = rest / KB, kbi = rest - tile * KB;
    int l16 = lane & 15, quad = lane >> 4;
    int n = tile * 16 + l16;
    int kk = kbi * 32 + quad * 8 + j;
    dst[i] = f2bu(raw_at(src, (size_t)kk * N + n, isbf));
}

__global__ void preprocess(Segs S, const int* __restrict__ flags,
                           float* __restrict__ conv, int total,
                           u16* __restrict__ eah,
                           u16* __restrict__ wt2l, u16* __restrict__ wt2r,
                           u16* __restrict__ wt3l, u16* __restrict__ wt3r,
                           int* __restrict__ deg, float* __restrict__ poolcnt) {
    int i = blockIdx.x * blockDim.x + threadIdx.x;
    bool isbf = flags[0] != 0;
    if (i < total) {
        int lo = 0, hi = 29;
        while (hi - lo > 1) {
            int mid = (lo + hi) >> 1;
            if (i >= S.off[mid]) lo = mid; else hi = mid;
        }
        conv[i] = raw_at(S.src[lo], i - S.off[lo], isbf);
        return;
    }
    i -= total;
    if (i < NEDGES * 4) {                       // edge_attr -> bf16 (raw read)
        eah[i] = isbf ? ((const u16*)S.src[1])[i] : f2bu(((const float*)S.src[1])[i]);
        return;
    }
    i -= NEDGES * 4;
    if (i < 65536) { wtp_store(wt2l, S.src[9],  256, 256, i, isbf); return; }
    i -= 65536;
    if (i < 65536) { wtp_store(wt2r, S.src[11], 256, 256, i, isbf); return; }
    i -= 65536;
    if (i < 16384) { wtp_store(wt3l, S.src[16], 256, 64, i, isbf); return; }
    i -= 16384;
    if (i < 16384) { wtp_store(wt3r, S.src[18], 256, 64, i, isbf); return; }
    i -= 16384;
    if (i < NNODES) { deg[i] = 0; return; }
    i -= NNODES;
    if (i < NGRAPH * 65) poolcnt[i] = 0.f;
}

// ---------------------------------------------------------------------------
// CSR build: histogram -> shfl-scan -> scatter (dst-sorted edge list).
// CSR entry is int4 (src, ea01, ea23, pad): all edge metadata in one
// sequential 16B load for the agg kernels. (Round-12 per-dst src-sort
// REVERTED: sort cost + CSR rewrite traffic exceeded the locality gain --
// gather FETCH is already near the compulsory bound.)
// ---------------------------------------------------------------------------
__global__ void csr_hist(const void* __restrict__ ei, const int* __restrict__ flags,
                         int* __restrict__ deg) {
    int e = blockIdx.x * blockDim.x + threadIdx.x;
    if (e >= NEDGES) return;
    atomicAdd(&deg[idx_at(ei, NEDGES + e, flags[1])], 1);
}

__global__ void csr_scan(const int* __restrict__ deg, int* __restrict__ rowptr,
                         int* __restrict__ cursor) {
    __shared__ int wsum[16];
    __shared__ int wpre[16];
    const int t = threadIdx.x;
    const int wid = t >> 6, lane = t & 63;
    const int base = t * 20;
    int loc[20];
    int s = 0;
#pragma unroll
    for (int j = 0; j < 20; j++) {
        int i = base + j;
        int v = (i < NNODES) ? deg[i] : 0;
        loc[j] = s;
        s += v;
    }
    int incl = s;
#pragma unroll
    for (int o = 1; o < 64; o <<= 1) {
        int n = __shfl_up(incl, o);
        if (lane >= o) incl += n;
    }
    if (lane == 63) wsum[wid] = incl;
    __syncthreads();
    if (wid == 0 && lane < 16) {
        int v = wsum[lane];
        int inc2 = v;
#pragma unroll
        for (int o = 1; o < 16; o <<= 1) {
            int n = __shfl_up(inc2, o);
            if (lane >= o) inc2 += n;
        }
        wpre[lane] = inc2 - v;
    }
    __syncthreads();
    int excl = wpre[wid] + incl - s;
#pragma unroll
    for (int j = 0; j < 20; j++) {
        int i = base + j;
        if (i < NNODES) { rowptr[i] = excl + loc[j]; cursor[i] = excl + loc[j]; }
    }
    if (t == 1023) rowptr[NNODES] = excl + s;
}

__global__ void csr_scatter(const void* __restrict__ ei, const int* __restrict__ flags,
                            const u16* __restrict__ eah,
                            int* __restrict__ cursor, int4* __restrict__ csr) {
    int e = blockIdx.x * blockDim.x + threadIdx.x;
    if (e >= NEDGES) return;
    const int i64 = flags[1];
    int src = idx_at(ei, e, i64), dst = idx_at(ei, NEDGES + e, i64);
    uint2 au = *(const uint2*)&eah[(size_t)e * 4];
    int pos = atomicAdd(&cursor[dst], 1);
    csr[pos] = make_int4(src, (int)au.x, (int)au.y, 0);
}

// ---------------------------------------------------------------------------
// VALU GEMM (layer 1, CIN=12): XL = X@Wl+bl (bf16), XR = X@Wr+br (fp32)
// ---------------------------------------------------------------------------
template <int TM, int CIN, int DOUT, bool GUARD>
__global__ __launch_bounds__(256, 2) void lin_gemm(
        const float* __restrict__ X,
        const float* __restrict__ Wl, const float* __restrict__ bl,
        const float* __restrict__ Wr, const float* __restrict__ br,
        u16* __restrict__ XL, float* __restrict__ XR) {
    constexpr int CPT = DOUT / 4;
    constexpr int RG = 256 / CPT;
    constexpr int M = RG * TM;
    __shared__ float xs[M * CIN];

    const int t = threadIdx.x;
    const int ct = t % CPT;
    const int rg = t / CPT;
    const int c0 = ct * 4;
    const int r0 = blockIdx.x * M;

    constexpr int C4 = CIN / 4;
    for (int i = t; i < M * C4; i += 256) {
        int r = i / C4, j = i - r * C4;
        float4 v = make_float4(0.f, 0.f, 0.f, 0.f);
        if (!GUARD || (r0 + r) < NNODES)
            v = *(const float4*)&X[(size_t)(r0 + r) * CIN + j * 4];
        *(float4*)&xs[r * CIN + j * 4] = v;
    }
    __syncthreads();

    float4 accL[TM], accR[TM];
#pragma unroll
    for (int m = 0; m < TM; m++) {
        accL[m] = make_float4(0.f, 0.f, 0.f, 0.f);
        accR[m] = make_float4(0.f, 0.f, 0.f, 0.f);
    }
    const float* xbase = &xs[rg * TM * CIN];
#pragma unroll 4
    for (int k = 0; k < CIN; k++) {
        const float4 wl = *(const float4*)&Wl[k * DOUT + c0];
        const float4 wr = *(const float4*)&Wr[k * DOUT + c0];
#pragma unroll
        for (int m = 0; m < TM; m++) {
            float xv = xbase[m * CIN + k];
            accL[m].x = fmaf(xv, wl.x, accL[m].x);
            accL[m].y = fmaf(xv, wl.y, accL[m].y);
            accL[m].z = fmaf(xv, wl.z, accL[m].z);
            accL[m].w = fmaf(xv, wl.w, accL[m].w);
            accR[m].x = fmaf(xv, wr.x, accR[m].x);
            accR[m].y = fmaf(xv, wr.y, accR[m].y);
            accR[m].z = fmaf(xv, wr.z, accR[m].z);
            accR[m].w = fmaf(xv, wr.w, accR[m].w);
        }
    }

    const float4 b4l = *(const float4*)&bl[c0];
    const float4 b4r = *(const float4*)&br[c0];
#pragma unroll
    for (int m = 0; m < TM; m++) {
        int row = r0 + rg * TM + m;
        if (GUARD && row >= NNODES) continue;
        float l0 = accL[m].x + b4l.x, l1 = accL[m].y + b4l.y;
        float l2 = accL[m].z + b4l.z, l3 = accL[m].w + b4l.w;
        uint2 pk;
        pk.x = (unsigned)f2bu(l0) | ((unsigned)f2bu(l1) << 16);
        pk.y = (unsigned)f2bu(l2) | ((unsigned)f2bu(l3) << 16);
        *(uint2*)&XL[(size_t)row * DOUT + c0] = pk;
        float4 r4;
        r4.x = accR[m].x + b4r.x; r4.y = accR[m].y + b4r.y;
        r4.z = accR[m].z + b4r.z; r4.w = accR[m].w + b4r.w;
        *(float4*)&XR[(size_t)row * DOUT + c0] = r4;
    }
}

// ---------------------------------------------------------------------------
// MFMA GEMM (layers 2/3): XL = X@Wl+bl (bf16 out), XR = X@Wr+br (fp32 out).
// ---------------------------------------------------------------------------
template <int N>
__global__ __launch_bounds__(256) void lin_gemm_mfma(
        const float* __restrict__ X,
        const u16* __restrict__ WlP, const float* __restrict__ bl,
        const u16* __restrict__ WrP, const float* __restrict__ br,
        u16* __restrict__ XL, float* __restrict__ XR) {
    constexpr int K = 256;
    constexpr int KB = K / 32;
    constexpr int NTW = N / 64;
    constexpr int XSTR = 264;
    __shared__ u16 xhi[16 * XSTR];
    __shared__ u16 xlo[16 * XSTR];

    const int t = threadIdx.x;
    const int w = t >> 6, lane = t & 63;
    const int quad = lane >> 4, l16 = lane & 15;
    const int m0 = blockIdx.x * 16;
    const int nbase = w * (N / 4);

    for (int idx = t; idx < 16 * 64; idx += 256) {
        int r = idx >> 6, c4 = idx & 63;
        float4 v = *(const float4*)&X[(size_t)(m0 + r) * K + c4 * 4];
        float f[4] = {v.x, v.y, v.z, v.w};
        ushort4 hi, lo;
        u16 h;
        h = f2bu(f[0]); hi.x = h; lo.x = f2bu(f[0] - bu2f(h));
        h = f2bu(f[1]); hi.y = h; lo.y = f2bu(f[1] - bu2f(h));
        h = f2bu(f[2]); hi.z = h; lo.z = f2bu(f[2] - bu2f(h));
        h = f2bu(f[3]); hi.w = h; lo.w = f2bu(f[3] - bu2f(h));
        *(ushort4*)&xhi[r * XSTR + c4 * 4] = hi;
        *(ushort4*)&xlo[r * XSTR + c4 * 4] = lo;
    }
    __syncthreads();

    f32x4 accL[NTW], accR[NTW];
#pragma unroll
    for (int i = 0; i < NTW; i++) {
        accL[i] = (f32x4){0.f, 0.f, 0.f, 0.f};
        accR[i] = (f32x4){0.f, 0.f, 0.f, 0.f};
    }

    const int abase = l16 * XSTR + quad * 8;
#pragma unroll
    for (int kbi = 0; kbi < KB; kbi++) {
        short8 ahi = *(const short8*)&xhi[abase + kbi * 32];
        short8 alo = *(const short8*)&xlo[abase + kbi * 32];
#pragma unroll
        for (int i = 0; i < NTW; i++) {
            int tg = (nbase >> 4) + i;
            size_t off = ((size_t)(tg * KB + kbi) * 64 + lane) * 8;
            short8 bL = *(const short8*)&WlP[off];
            short8 bR = *(const short8*)&WrP[off];
            accL[i] = __builtin_amdgcn_mfma_f32_16x16x32_bf16(ahi, bL, accL[i], 0, 0, 0);
            accL[i] = __builtin_amdgcn_mfma_f32_16x16x32_bf16(alo, bL, accL[i], 0, 0, 0);
            accR[i] = __builtin_amdgcn_mfma_f32_16x16x32_bf16(ahi, bR, accR[i], 0, 0, 0);
            accR[i] = __builtin_amdgcn_mfma_f32_16x16x32_bf16(alo, bR, accR[i], 0, 0, 0);
        }
    }

#pragma unroll
    for (int i = 0; i < NTW; i++) {
        int col = nbase + i * 16 + l16;
        float bLv = bl[col], bRv = br[col];
#pragma unroll
        for (int r = 0; r < 4; r++) {
            int row = m0 + quad * 4 + r;
            XL[(size_t)row * N + col] = f2bu(accL[i][r] + bLv);
            XR[(size_t)row * N + col] = accR[i][r] + bRv;
        }
    }
}

// ---------------------------------------------------------------------------
// Merged-wave GATv2 aggregation, scalarized, packed-f32 math (layers 1/2,
// H=4): one WAVE per dst, all 256 channels (4/lane), 8 edges per iter.
// csr/attrs wave-uniform (scalar loads, SGPR operands); VOP3P dual-FP32
// channel math; DPP rowsum16 reduce.
// ---------------------------------------------------------------------------
template <bool ELU>
__global__ __launch_bounds__(256, 2) void gat_agg_mw(
        const int* __restrict__ rowptr, const int4* __restrict__ csr,
        const u16* __restrict__ XL, const float* __restrict__ XR,
        const float* __restrict__ We, const float* __restrict__ att,
        const float* __restrict__ bias, float* __restrict__ out) {
    const int lane = threadIdx.x & 63;
    const int dst = rfl(blockIdx.x * 4 + (threadIdx.x >> 6));
    const int c0 = lane * 4;                 // head = lane>>4, 4 channels/lane

    const float4 w0 = *(const float4*)&We[0 * 256 + c0];
    const float4 w1 = *(const float4*)&We[1 * 256 + c0];
    const float4 w2 = *(const float4*)&We[2 * 256 + c0];
    const float4 w3 = *(const float4*)&We[3 * 256 + c0];
    const float4 at = *(const float4*)&att[c0];
    const float4 xr = *(const float4*)&XR[(size_t)dst * 256 + c0];
    const f32x2 w0a = {w0.x, w0.y}, w0b = {w0.z, w0.w};
    const f32x2 w1a = {w1.x, w1.y}, w1b = {w1.z, w1.w};
    const f32x2 w2a = {w2.x, w2.y}, w2b = {w2.z, w2.w};
    const f32x2 w3a = {w3.x, w3.y}, w3b = {w3.z, w3.w};
    const f32x2 ata = {at.x, at.y}, atb = {at.z, at.w};
    const f32x2 xra = {xr.x, xr.y}, xrb = {xr.z, xr.w};

    const int i0 = rfl(rowptr[dst]);
    const int i1 = rfl(rowptr[dst + 1]);

    float l = 0.f;
    f32x2 accA = {0.f, 0.f}, accB = {0.f, 0.f};

    // A0..A3 uniform (SGPR) floats; xu is the per-lane 8B gather.
#define MW_BODY(XU, A0, A1, A2, A3)                                              \
    {                                                                            \
        f32x2 xlA = {__uint_as_float((XU).x << 16),                              \
                     __uint_as_float((XU).x & 0xffff0000u)};                     \
        f32x2 xlB = {__uint_as_float((XU).y << 16),                              \
                     __uint_as_float((XU).y & 0xffff0000u)};                     \
        f32x2 zA = xlA + xra;                                                    \
        zA = A0 * w0a + zA;                                                      \
        zA = A1 * w1a + zA;                                                      \
        zA = A2 * w2a + zA;                                                      \
        zA = A3 * w3a + zA;                                                      \
        f32x2 zB = xlB + xrb;                                                    \
        zB = A0 * w0b + zB;                                                      \
        zB = A1 * w1b + zB;                                                      \
        zB = A2 * w2b + zB;                                                      \
        zB = A3 * w3b + zB;                                                      \
        zA = __builtin_elementwise_max(zA, 0.2f * zA);                           \
        zB = __builtin_elementwise_max(zB, 0.2f * zB);                           \
        f32x2 dv = zA * ata;                                                     \
        dv = zB * atb + dv;                                                      \
        float v = dv.x + dv.y;                                                   \
        v = rowsum16(v);                                                         \
        float p = __expf(v);                                                     \
        l += p;                                                                  \
        accA = p * xlA + accA;                                                   \
        accB = p * xlB + accB;                                                   \
    }

// one sequential 16B CSR entry -> src (gather addr) + 4 uniform attrs
#define MW_LOAD(K)                                                               \
        int4 t##K = csr[e + K];                                                  \
        int sx##K = rfl(t##K.x);                                                 \
        uint2 xu##K = *(const uint2*)&XL[(size_t)sx##K * 256 + c0];              \
        float a##K##0 = __uint_as_float(rfl((int)((unsigned)t##K.y << 16)));     \
        float a##K##1 = __uint_as_float(rfl((int)((unsigned)t##K.y & 0xffff0000u))); \
        float a##K##2 = __uint_as_float(rfl((int)((unsigned)t##K.z << 16)));     \
        float a##K##3 = __uint_as_float(rfl((int)((unsigned)t##K.z & 0xffff0000u)));

    int e = i0;
    for (; e + 8 <= i1; e += 8) {
        MW_LOAD(0) MW_LOAD(1) MW_LOAD(2) MW_LOAD(3)
        MW_LOAD(4) MW_LOAD(5) MW_LOAD(6) MW_LOAD(7)
        MW_BODY(xu0, a00, a01, a02, a03)
        MW_BODY(xu1, a10, a11, a12, a13)
        MW_BODY(xu2, a20, a21, a22, a23)
        MW_BODY(xu3, a30, a31, a32, a33)
        MW_BODY(xu4, a40, a41, a42, a43)
        MW_BODY(xu5, a50, a51, a52, a53)
        MW_BODY(xu6, a60, a61, a62, a63)
        MW_BODY(xu7, a70, a71, a72, a73)
    }
    for (; e + 4 <= i1; e += 4) {
        MW_LOAD(0) MW_LOAD(1) MW_LOAD(2) MW_LOAD(3)
        MW_BODY(xu0, a00, a01, a02, a03)
        MW_BODY(xu1, a10, a11, a12, a13)
        MW_BODY(xu2, a20, a21, a22, a23)
        MW_BODY(xu3, a30, a31, a32, a33)
    }
    for (; e < i1; ++e) {
        MW_LOAD(0)
        MW_BODY(xu0, a00, a01, a02, a03)
    }
#undef MW_LOAD
#undef MW_BODY

    // l is already uniform within each 16-lane head group; acc is per-channel.
    float inv = 1.f / (l + 1e-16f);
    const float4 b4 = *(const float4*)&bias[c0];
    f32x2 oA = accA * inv + (f32x2){b4.x, b4.y};
    f32x2 oB = accB * inv + (f32x2){b4.z, b4.w};
    float o0 = oA.x, o1 = oA.y, o2 = oB.x, o3 = oB.y;
    if (ELU) {
        o0 = o0 > 0.f ? o0 : expf(o0) - 1.f;
        o1 = o1 > 0.f ? o1 : expf(o1) - 1.f;
        o2 = o2 > 0.f ? o2 : expf(o2) - 1.f;
        o3 = o3 > 0.f ? o3 : expf(o3) - 1.f;
    }
    *(float4*)&out[(size_t)dst * 256 + c0] = make_float4(o0, o1, o2, o3);
}

// ---------------------------------------------------------------------------
// Layer-3 aggregation (H=1, Dout=64), 4 dst per block, plain-store epilogue
// (pool atomics removed round 6: they were a 46us coherence wall).
// Edge attrs from the int4 CSR entry; packed-f32 channel math.
// ---------------------------------------------------------------------------
template <bool ELU>
__global__ __launch_bounds__(256, 4) void gat_agg4(
                        const int* __restrict__ rowptr, const int4* __restrict__ csr,
                        const u16* __restrict__ XL, const float* __restrict__ XR,
                        const float* __restrict__ We, const float* __restrict__ att,
                        const float* __restrict__ bias, float* __restrict__ out) {
    const int t = threadIdx.x;
    const int lane = t & 63;
    const int g = lane >> 4;         // edge-group 0..3
    const int k = lane & 15;         // channel-slot
    const int c0 = k * 4;            // this lane's 4 channels of 64
    const int dst = rfl(blockIdx.x * 4 + (t >> 6));   // uniform per wave

    const float4 w0 = *(const float4*)&We[0 * 64 + c0];
    const float4 w1 = *(const float4*)&We[1 * 64 + c0];
    const float4 w2 = *(const float4*)&We[2 * 64 + c0];
    const float4 w3 = *(const float4*)&We[3 * 64 + c0];
    const float4 at = *(const float4*)&att[c0];
    const float4 xr = *(const float4*)&XR[(size_t)dst * 64 + c0];
    const f32x2 w0a = {w0.x, w0.y}, w0b = {w0.z, w0.w};
    const f32x2 w1a = {w1.x, w1.y}, w1b = {w1.z, w1.w};
    const f32x2 w2a = {w2.x, w2.y}, w2b = {w2.z, w2.w};
    const f32x2 w3a = {w3.x, w3.y}, w3b = {w3.z, w3.w};
    const f32x2 ata = {at.x, at.y}, atb = {at.z, at.w};
    const f32x2 xra = {xr.x, xr.y}, xrb = {xr.z, xr.w};

    const int i0 = rfl(rowptr[dst]);
    const int i1 = rfl(rowptr[dst + 1]);
    const int niter = (i1 - i0 + 3) >> 2;

    float l = 0.f;
    f32x2 accA = {0.f, 0.f}, accB = {0.f, 0.f};

#define G4_BODY(E_IDX)                                                           \
    {                                                                            \
        int e_ = (E_IDX);                                                        \
        bool valid_ = e_ < i1;                                                   \
        int4 se_ = csr[valid_ ? e_ : i0];                                        \
        uint2 xu_ = *(const uint2*)&XL[(size_t)se_.x * 64 + c0];                 \
        float A0_ = __uint_as_float((unsigned)se_.y << 16);                      \
        float A1_ = __uint_as_float((unsigned)se_.y & 0xffff0000u);              \
        float A2_ = __uint_as_float((unsigned)se_.z << 16);                      \
        float A3_ = __uint_as_float((unsigned)se_.z & 0xffff0000u);              \
        f32x2 xlA = {__uint_as_float(xu_.x << 16),                               \
                     __uint_as_float(xu_.x & 0xffff0000u)};                      \
        f32x2 xlB = {__uint_as_float(xu_.y << 16),                               \
                     __uint_as_float(xu_.y & 0xffff0000u)};                      \
        f32x2 zA = xlA + xra;                                                    \
        zA = A0_ * w0a + zA;                                                     \
        zA = A1_ * w1a + zA;                                                     \
        zA = A2_ * w2a + zA;                                                     \
        zA = A3_ * w3a + zA;                                                     \
        f32x2 zB = xlB + xrb;                                                    \
        zB = A0_ * w0b + zB;                                                     \
        zB = A1_ * w1b + zB;                                                     \
        zB = A2_ * w2b + zB;                                                     \
        zB = A3_ * w3b + zB;                                                     \
        zA = __builtin_elementwise_max(zA, 0.2f * zA);                           \
        zB = __builtin_elementwise_max(zB, 0.2f * zB);                           \
        f32x2 dv = zA * ata;                                                     \
        dv = zB * atb + dv;                                                      \
        float v_ = dv.x + dv.y;                                                  \
        v_ = rowsum16(v_);                                                       \
        float p_ = valid_ ? __expf(v_) : 0.f;                                    \
        l += p_;                                                                 \
        accA = p_ * xlA + accA;                                                  \
        accB = p_ * xlB + accB;                                                  \
    }

    int it = 0;
    for (; it + 2 <= niter; it += 2) {
        int eb = i0 + g + it * 4;
        G4_BODY(eb)
        G4_BODY(eb + 4)
    }
    if (it < niter) {
        G4_BODY(i0 + g + it * 4)
    }
#undef G4_BODY

    // combine the 4 edge-groups (once per dst)
    l += __shfl_xor(l, 16);      l += __shfl_xor(l, 32);
    accA.x += __shfl_xor(accA.x, 16); accA.x += __shfl_xor(accA.x, 32);
    accA.y += __shfl_xor(accA.y, 16); accA.y += __shfl_xor(accA.y, 32);
    accB.x += __shfl_xor(accB.x, 16); accB.x += __shfl_xor(accB.x, 32);
    accB.y += __shfl_xor(accB.y, 16); accB.y += __shfl_xor(accB.y, 32);

    if (g == 0) {
        float inv = 1.f / (l + 1e-16f);
        const float4 b4 = *(const float4*)&bias[c0];
        float o0 = fmaf(accA.x, inv, b4.x);
        float o1 = fmaf(accA.y, inv, b4.y);
        float o2 = fmaf(accB.x, inv, b4.z);
        float o3 = fmaf(accB.y, inv, b4.w);
        if (ELU) {
            o0 = o0 > 0.f ? o0 : expf(o0) - 1.f;
            o1 = o1 > 0.f ? o1 : expf(o1) - 1.f;
            o2 = o2 > 0.f ? o2 : expf(o2) - 1.f;
            o3 = o3 > 0.f ? o3 : expf(o3) - 1.f;
        }
        *(float4*)&out[(size_t)dst * 64 + c0] = make_float4(o0, o1, o2, o3);
    }
}

// ---------------------------------------------------------------------------
// Fused segmented-mean pool + MLP head: one block (64 threads) per graph.
// batch is SORTED -> contiguous node ranges; zero atomics.
// ---------------------------------------------------------------------------
__global__ void pool_mlp(const float* __restrict__ h,  // [N][64]
                         const void* __restrict__ batch, const int* __restrict__ flags,
                         const float* __restrict__ mW1, const float* __restrict__ mb1,
                         const float* __restrict__ mW2, const float* __restrict__ mb2,
                         const float* __restrict__ mW3, const float* __restrict__ mb3,
                         float* __restrict__ out) {
    __shared__ int se[2];
    __shared__ float g[64], s1[32], s2[16];
    const int b = blockIdx.x, t = threadIdx.x;
    const int is64 = flags[2];
    if (t < 2) {
        // lower_bound(batch, b + t): first i with batch[i] >= target
        int target = b + t;
        int lo = 0, hi = NNODES;
        while (lo < hi) {
            int mid = (lo + hi) >> 1;
            if (idx_at(batch, mid, is64) < target) lo = mid + 1; else hi = mid;
        }
        se[t] = lo;
    }
    __syncthreads();
    const int s = se[0], e = se[1];
    float a = 0.f;
    for (int i = s; i < e; i++) a += h[(size_t)i * 64 + t];
    g[t] = a / fmaxf((float)(e - s), 1.f);
    __syncthreads();
    if (t < 32) {
        float acc = 0.f;
        for (int k = 0; k < 64; k++) acc = fmaf(g[k], mW1[k * 32 + t], acc);
        s1[t] = fmaxf(acc + mb1[t], 0.f);
    }
    __syncthreads();
    if (t < 16) {
        float acc = 0.f;
        for (int k = 0; k < 32; k++) acc = fmaf(s1[k], mW2[k * 16 + t], acc);
        s2[t] = fmaxf(acc + mb2[t], 0.f);
    }
    __syncthreads();
    if (t < 4) {
        float acc = 0.f;
        for (int k = 0; k < 16; k++) acc = fmaf(s2[k], mW3[k * 4 + t], acc);
        out[b * 4 + t] = acc + mb3[t];
    }
}

// ---------------------------------------------------------------------------

extern "C" void kernel_launch(void* const* d_in, const int* in_sizes, int n_in,
                              void* d_out, int out_size, void* d_ws, size_t ws_size,
                              hipStream_t stream) {
    const void* ei    = d_in[1];
    const void* batch = d_in[3];

    // ---- canonicalization table: the 29 float inputs in dict order ----
    int fidx[29];
    fidx[0] = 0;  // x
    fidx[1] = 2;  // edge_attr
    for (int i = 0; i < 21; i++) fidx[2 + i] = 4 + i;
    for (int i = 0; i < 6; i++) fidx[23 + i] = 25 + i;

    Segs S;
    int off = 0;
    for (int i = 0; i < 29; i++) {
        S.src[i] = d_in[fidx[i]];
        S.off[i] = off;
        off += in_sizes[fidx[i]];
    }
    S.off[29] = off;
    const int total = off;

    // ---- workspace layout (16B-aligned sections) ----
    char* p = (char*)d_ws;
    int*   FLAGS  = (int*)p;                 p += 16;
    float* CONV   = (float*)p;               p += sizeof(float) * total;  p = align16(p);
    int*   DEG    = (int*)p;                 p += sizeof(int) * NNODES;
    int*   ROWPTR = (int*)p;                 p += sizeof(int) * (NNODES + 1);
    int*   CURSOR = (int*)p;                 p += sizeof(int) * (NNODES + 1);  p = align16(p);
    int4*  CSR    = (int4*)p;                p += sizeof(int4) * NEDGES;  p = align16(p);
    u16*   EAH    = (u16*)p;                 p += sizeof(u16) * NEDGES * 4;  p = align16(p);
    u16*   WT2L   = (u16*)p;                 p += sizeof(u16) * 256 * 256;
    u16*   WT2R   = (u16*)p;                 p += sizeof(u16) * 256 * 256;
    u16*   WT3L   = (u16*)p;                 p += sizeof(u16) * 64 * 256;
    u16*   WT3R   = (u16*)p;                 p += sizeof(u16) * 64 * 256;  p = align16(p);
    u16*   XLb    = (u16*)p;                 p += sizeof(u16) * NNODES * 256;  p = align16(p);
    float* XRb    = (float*)p;               p += sizeof(float) * NNODES * 256;
    float* ACC    = (float*)p;               p += sizeof(float) * NNODES * 256;
    float* POOL   = (float*)p;               p += sizeof(float) * NGRAPH * 64;
    float* CNT    = (float*)p;               p += sizeof(float) * NGRAPH;

    const float* CX  = CONV + S.off[0];
    const float* CP[21];
    for (int i = 0; i < 21; i++) CP[i] = CONV + S.off[2 + i];
    const float* CmW1 = CONV + S.off[23];
    const float* Cmb1 = CONV + S.off[24];
    const float* CmW2 = CONV + S.off[25];
    const float* Cmb2 = CONV + S.off[26];
    const float* CmW3 = CONV + S.off[27];
    const float* Cmb3 = CONV + S.off[28];

    // ---- sniff + fused preprocessing (convert/ea/W-pack/zero-init) ----
    sniff_all<<<1, 256, 0, stream>>>(d_in[0], ei, batch, FLAGS);
    int pre_total = total + NEDGES * 4 + 65536 * 2 + 16384 * 2 + NNODES + NGRAPH * 65;
    preprocess<<<(pre_total + 255) / 256, 256, 0, stream>>>(
        S, FLAGS, CONV, total, EAH, WT2L, WT2R, WT3L, WT3R, DEG, POOL);

    // ---- CSR build (graph identical across layers: build once; attrs folded in) ----
    csr_hist<<<(NEDGES + 255) / 256, 256, 0, stream>>>(ei, FLAGS, DEG);
    csr_scan<<<1, 1024, 0, stream>>>(DEG, ROWPTR, CURSOR);
    csr_scatter<<<(NEDGES + 255) / 256, 256, 0, stream>>>(ei, FLAGS, EAH, CURSOR, CSR);

    // ---- layer 1: x (N x 12) -> ACC (N x 256), ELU ----
    lin_gemm<4, 12, 256, false><<<NNODES / 16, 256, 0, stream>>>(CX, CP[0], CP[1], CP[2], CP[3], XLb, XRb);
    gat_agg_mw<true><<<NNODES / 4, 256, 0, stream>>>(ROWPTR, CSR, XLb, XRb,
        CP[4], CP[5], CP[6], ACC);

    // ---- layer 2: ACC (N x 256) -> ACC, ELU (MFMA GEMM) ----
    lin_gemm_mfma<256><<<NNODES / 16, 256, 0, stream>>>(ACC, WT2L, CP[8], WT2R, CP[10], XLb, XRb);
    gat_agg_mw<true><<<NNODES / 4, 256, 0, stream>>>(ROWPTR, CSR, XLb, XRb,
        CP[11], CP[12], CP[13], ACC);

    // ---- layer 3: ACC (N x 256) -> h (N x 64), plain stores (no atomics) ----
    lin_gemm_mfma<64><<<NNODES / 16, 256, 0, stream>>>(ACC, WT3L, CP[15], WT3R, CP[17], XLb, XRb);
    gat_agg4<false><<<NNODES / 4, 256, 0, stream>>>(ROWPTR, CSR, XLb, XRb,
        CP[18], CP[19], CP[20], ACC);

    // ---- segmented mean-pool (sorted batch) + MLP head, fused ----
    pool_mlp<<<NGRAPH, 64, 0, stream>>>(ACC, batch, FLAGS,
        CmW1, Cmb1, CmW2, Cmb2, CmW3, Cmb3, (float*)d_out);
}